// Round 12
// baseline (235.091 us; speedup 1.0000x reference)
//
#include <hip/hip_runtime.h>

// ---- ws layout (float offsets) ----
constexpr int F_ELEMS = 4 * 32 * 4 * 48;            // padded-48 conv1 tables
constexpr int PREDS_OFF = F_ELEMS;                  // 24576
constexpr int RBCP_OFF = PREDS_OFF + 1024 * 256;    // rbc_part[64][32]
constexpr int CNT_OFF = RBCP_OFF + 2048;            // completion counter (+pad)
constexpr int W1P_OFF = CNT_OFF + 16;               // fc1 A-frags: 8192 shorts
constexpr int W2P_OFF = W1P_OFF + 4096;             // fc2 A-frags: 65536 shorts
constexpr int W3P_OFF = W2P_OFF + 32768;            // fc3 A-frags: 65536 shorts

typedef __attribute__((ext_vector_type(8))) short short8;
typedef __attribute__((ext_vector_type(4))) short short4v;
typedef __attribute__((ext_vector_type(4))) float f32x4;

__device__ __forceinline__ unsigned short f2bf(float x) {  // RNE bf16
    unsigned u = __float_as_uint(x);
    u += 0x7FFF + ((u >> 16) & 1);
    return (unsigned short)(u >> 16);
}
__device__ __forceinline__ float bf2f(unsigned short h) {
    return __uint_as_float(((unsigned)h) << 16);
}

// ---------------- Kernel 0: all preprocessing (r9-verified) ----------------
__global__ void prep_all(const float* __restrict__ emb, const float* __restrict__ w1,
                         const float* __restrict__ fc1_w, const float* __restrict__ fc2_w,
                         const float* __restrict__ fc3_w,
                         float* __restrict__ F, unsigned short* __restrict__ W1p,
                         unsigned short* __restrict__ W2p, unsigned short* __restrict__ W3p,
                         float* __restrict__ rbcp_zero) {
    int b = blockIdx.x;
    if (b < 96) {
        int idx = b * 256 + threadIdx.x;  // 24576
        int i = idx % 48;
        int o = (idx / 48) % 4;
        int node = (idx / 192) % 32;
        int c = idx / 6144;
        float acc = 0.f;
        if (i < 46) {
#pragma unroll
            for (int k = 0; k < 3; k++) acc += w1[(o * 4 + c) * 3 + k] * emb[node * 96 + 2 * i + k];
        }
        F[idx] = acc;
        return;
    }
    if (b < 128) {  // fc1 A-layout, K padded 16->32
        int t = (b - 96) * 256 + threadIdx.x;  // 8192
        int j = t & 7, lane = (t >> 3) & 63, term = (t >> 9) & 1, mt = t >> 10;
        int k = (lane >> 4) * 8 + j, n = mt * 16 + (lane & 15);
        float w = (k < 16) ? fc1_w[k * 128 + n] : 0.f;
        unsigned short hi = f2bf(w);
        W1p[t] = (term == 0) ? hi : f2bf(w - bf2f(hi));
        return;
    }
    if (b < 384) {  // fc2 A-layout [16mt][4ks][2term]
        int t = (b - 128) * 256 + threadIdx.x;  // 65536
        int j = t & 7, lane = (t >> 3) & 63, term = (t >> 9) & 1, ks = (t >> 10) & 3, mt = t >> 12;
        int k = ks * 32 + (lane >> 4) * 8 + j, n = mt * 16 + (lane & 15);
        float w = fc2_w[k * 256 + n];
        unsigned short hi = f2bf(w);
        W2p[t] = (term == 0) ? hi : f2bf(w - bf2f(hi));
        return;
    }
    if (b < 640) {  // fc3 A-layout [8mt][8ks][2term]
        int t = (b - 384) * 256 + threadIdx.x;  // 65536
        int j = t & 7, lane = (t >> 3) & 63, term = (t >> 9) & 1, ks = (t >> 10) & 7, mt = t >> 13;
        int k = ks * 32 + (lane >> 4) * 8 + j, n = mt * 16 + (lane & 15);
        float w = fc3_w[k * 128 + n];
        unsigned short hi = f2bf(w);
        W3p[t] = (term == 0) ? hi : f2bf(w - bf2f(hi));
        return;
    }
    for (int k = threadIdx.x; k < 2064; k += 256) rbcp_zero[k] = 0.f;  // rbc_part + counter
}

// ---------------- Kernel 1: mlp, grid 4096, ONE 64-sample set per block (r10 lesson: no chunk
// loop — it spills to scratch). fc2->fc3 in FOUR 64-wide quarters through an 8 KB X3q buffer:
// LDS 25600 B -> 6 blocks/CU (was 4). Weight traffic per wave unchanged. ----------------
__global__ __launch_bounds__(256, 6)
void mlp_kernel(const float* __restrict__ F, const int* __restrict__ edges,
                const float* __restrict__ b1v,
                const float* __restrict__ w2, const float* __restrict__ b2,
                const float* __restrict__ w3, const float* __restrict__ b3,
                const float* __restrict__ fc1_b, const float* __restrict__ fc2_b,
                const float* __restrict__ fc3_b,
                const float* __restrict__ fc4_w, const float* __restrict__ fc4_b,
                const unsigned short* __restrict__ W1p, const unsigned short* __restrict__ W2p,
                const unsigned short* __restrict__ W3p,
                float* __restrict__ preds) {
    // LDS (floats): [0,2048) X3q region ([8g][64][8] shorts = 8 KB); X1 (4 KB) aliases its head
    //               [2048,6144) X2 bf16 [16g][64][8] (16 KB)
    //               [6144,6400) part[256]
    __shared__ __align__(16) float smem[6400];
    unsigned short* X1 = (unsigned short*)smem;
    unsigned short* X3q = (unsigned short*)smem;
    unsigned short* X2 = (unsigned short*)(smem + 2048);
    float* part = smem + 6144;

    const int tid = threadIdx.x;
    const int p = blockIdx.x >> 2;
    const int e0 = (blockIdx.x & 3) * 64;
    const int s = p >> 5, t = p & 31;
    if (s == t) return;

    const int gsample = tid >> 2, o = tid & 3;  // conv roles
    float h1[23];
    // ---- conv1: table sum (float4 loads, padded-48 rows) + pool -> regs ----
    {
        const int e = e0 + gsample;
        const int u = edges[2 * e], v = edges[2 * e + 1];
        const f32x4* F0 = (const f32x4*)(F + ((0 * 32 + s) * 4 + o) * 48);
        const f32x4* F1 = (const f32x4*)(F + ((1 * 32 + t) * 4 + o) * 48);
        const f32x4* F2 = (const f32x4*)(F + ((2 * 32 + u) * 4 + o) * 48);
        const f32x4* F3 = (const f32x4*)(F + ((3 * 32 + v) * 4 + o) * 48);
        const float bb = b1v[o];
        float pre[46];
#pragma unroll
        for (int q = 0; q < 12; q++) {
            f32x4 x = F0[q] + F1[q] + F2[q] + F3[q];
#pragma unroll
            for (int z = 0; z < 4; z++) {
                int i = 4 * q + z;
                if (i < 46) pre[i] = fmaxf(x[z] + bb, 0.f);
            }
        }
#pragma unroll
        for (int j = 0; j < 23; j++) h1[j] = fmaxf(pre[2 * j], pre[2 * j + 1]);
    }
    float h2[10];
    // ---- conv2: cross-channel via shfl_xor (4-lane groups), sliding ring ----
    {
        float wm[4][3];
#pragma unroll
        for (int m = 0; m < 4; m++)
#pragma unroll
            for (int k = 0; k < 3; k++) wm[m][k] = w2[o * 12 + (o ^ m) * 3 + k];
        const float bb = b2[o];
        float win[4][3];
#pragma unroll
        for (int j = 0; j < 2; j++) {
            float x = h1[j];
            win[0][j] = x;
            win[1][j] = __shfl_xor(x, 1, 64);
            win[2][j] = __shfl_xor(x, 2, 64);
            win[3][j] = __shfl_xor(x, 3, 64);
        }
        float pre[20];
#pragma unroll
        for (int i = 0; i < 20; i++) {
            float x = h1[i + 2];
            win[0][(i + 2) % 3] = x;
            win[1][(i + 2) % 3] = __shfl_xor(x, 1, 64);
            win[2][(i + 2) % 3] = __shfl_xor(x, 2, 64);
            win[3][(i + 2) % 3] = __shfl_xor(x, 3, 64);
            float acc = bb;
#pragma unroll
            for (int m = 0; m < 4; m++)
#pragma unroll
                for (int k = 0; k < 3; k++)
                    acc = fmaf(wm[m][k], win[m][(i + k) % 3], acc);
            pre[i] = fmaxf(acc, 0.f);
        }
#pragma unroll
        for (int j = 0; j < 10; j++) h2[j] = fmaxf(pre[2 * j], pre[2 * j + 1]);
    }
    // ---- conv3 + pool -> X1 (bf16 B-frag layout, K 16 padded to 32) ----
    {
        float wm[4][3];
#pragma unroll
        for (int m = 0; m < 4; m++)
#pragma unroll
            for (int k = 0; k < 3; k++) wm[m][k] = w3[o * 12 + (o ^ m) * 3 + k];
        const float bb = b3[o];
        float win[4][3];
#pragma unroll
        for (int j = 0; j < 2; j++) {
            float x = h2[j];
            win[0][j] = x;
            win[1][j] = __shfl_xor(x, 1, 64);
            win[2][j] = __shfl_xor(x, 2, 64);
            win[3][j] = __shfl_xor(x, 3, 64);
        }
        float pre[8];
#pragma unroll
        for (int i = 0; i < 8; i++) {
            float x = h2[i + 2];
            win[0][(i + 2) % 3] = x;
            win[1][(i + 2) % 3] = __shfl_xor(x, 1, 64);
            win[2][(i + 2) % 3] = __shfl_xor(x, 2, 64);
            win[3][(i + 2) % 3] = __shfl_xor(x, 3, 64);
            float acc = bb;
#pragma unroll
            for (int m = 0; m < 4; m++)
#pragma unroll
                for (int k = 0; k < 3; k++)
                    acc = fmaf(wm[m][k], win[m][(i + k) % 3], acc);
            pre[i] = fmaxf(acc, 0.f);
        }
        short4v pk;
#pragma unroll
        for (int l = 0; l < 4; l++)
            pk[l] = (short)f2bf(fmaxf(pre[2 * l], pre[2 * l + 1]));
        *(short4v*)(X1 + (((o >> 1) * 64 + gsample) * 8) + (o & 1) * 4) = pk;
        short4v z4 = (short4v){0, 0, 0, 0};
        *(short4v*)(X1 + ((((o >> 1) + 2) * 64 + gsample) * 8) + (o & 1) * 4) = z4;
    }
    __syncthreads();  // barrier 1: X1 visible
    const int lane = tid & 63, wave = tid >> 6;
    const int mrow = lane & 15, quad = lane >> 4;
    // ---- fc1 MFMA ----
    {
        const short8* W1v = (const short8*)W1p;
        short8 bnt[4];
#pragma unroll
        for (int nt = 0; nt < 4; nt++)
            bnt[nt] = *(const short8*)(X1 + (quad * 64 + nt * 16 + mrow) * 8);
        f32x4 acc1[2][4];
#pragma unroll
        for (int a = 0; a < 2; a++)
#pragma unroll
            for (int b = 0; b < 4; b++) acc1[a][b] = (f32x4){0.f, 0.f, 0.f, 0.f};
#pragma unroll
        for (int mtl = 0; mtl < 2; mtl++) {
            const int mt = wave * 2 + mtl;
            short8 ah = W1v[(mt * 2 + 0) * 64 + lane];
            short8 al = W1v[(mt * 2 + 1) * 64 + lane];
#pragma unroll
            for (int nt = 0; nt < 4; nt++) {
                acc1[mtl][nt] = __builtin_amdgcn_mfma_f32_16x16x32_bf16(ah, bnt[nt], acc1[mtl][nt], 0, 0, 0);
                acc1[mtl][nt] = __builtin_amdgcn_mfma_f32_16x16x32_bf16(al, bnt[nt], acc1[mtl][nt], 0, 0, 0);
            }
        }
#pragma unroll
        for (int mtl = 0; mtl < 2; mtl++) {
            const int mt = wave * 2 + mtl;
            const int n0 = mt * 16 + quad * 4;
            f32x4 b4 = *(const f32x4*)(fc1_b + n0);
#pragma unroll
            for (int nt = 0; nt < 4; nt++) {
                short4v pk;
#pragma unroll
                for (int r = 0; r < 4; r++)
                    pk[r] = (short)f2bf(fmaxf(acc1[mtl][nt][r] + b4[r], 0.f));
                *(short4v*)(X2 + ((n0 >> 3) * 64 + nt * 16 + mrow) * 8 + (n0 & 7)) = pk;
            }
        }
    }
    __syncthreads();  // barrier 2: X2 ready, X1 reads done (X3q writes may follow)
    // ---- fc2 -> fc3 in FOUR 64-output quarters through X3q ----
    const short8* W2v = (const short8*)W2p;
    const short8* W3v = (const short8*)W3p;
    f32x4 acc3[2][4];
#pragma unroll
    for (int a = 0; a < 2; a++)
#pragma unroll
        for (int b = 0; b < 4; b++) acc3[a][b] = (f32x4){0.f, 0.f, 0.f, 0.f};
#pragma unroll
    for (int q = 0; q < 4; q++) {
        // fc2 quarter: wave owns mt = q*4 + wave (one 16-output tile), full K=128 from X2
        const int mt2 = q * 4 + wave;
        f32x4 acc2[4];
#pragma unroll
        for (int b = 0; b < 4; b++) acc2[b] = (f32x4){0.f, 0.f, 0.f, 0.f};
#pragma unroll
        for (int ks = 0; ks < 4; ks++) {
            short8 bfr[4];
#pragma unroll
            for (int nt = 0; nt < 4; nt++)
                bfr[nt] = *(const short8*)(X2 + ((ks * 4 + quad) * 64 + nt * 16 + mrow) * 8);
            short8 ah = W2v[((mt2 * 4 + ks) * 2 + 0) * 64 + lane];
            short8 al = W2v[((mt2 * 4 + ks) * 2 + 1) * 64 + lane];
#pragma unroll
            for (int nt = 0; nt < 4; nt++) {
                acc2[nt] = __builtin_amdgcn_mfma_f32_16x16x32_bf16(ah, bfr[nt], acc2[nt], 0, 0, 0);
                acc2[nt] = __builtin_amdgcn_mfma_f32_16x16x32_bf16(al, bfr[nt], acc2[nt], 0, 0, 0);
            }
        }
        // epilogue -> X3q (k-local = n - q*64, in [0,64))
        {
            const int n0 = mt2 * 16 + quad * 4;
            const int kl = n0 - q * 64;
            f32x4 b4 = *(const f32x4*)(fc2_b + n0);
#pragma unroll
            for (int nt = 0; nt < 4; nt++) {
                short4v pk;
#pragma unroll
                for (int r = 0; r < 4; r++)
                    pk[r] = (short)f2bf(fmaxf(acc2[nt][r] + b4[r], 0.f));
                *(short4v*)(X3q + ((kl >> 3) * 64 + nt * 16 + mrow) * 8 + (kl & 7)) = pk;
            }
        }
        __syncthreads();  // X3q quarter ready
        // fc3 accumulate this quarter's 2 ks-groups (global ks = q*2+ksl)
#pragma unroll
        for (int ksl = 0; ksl < 2; ksl++) {
            const int ks = q * 2 + ksl;
            short8 bfr[4];
#pragma unroll
            for (int nt = 0; nt < 4; nt++)
                bfr[nt] = *(const short8*)(X3q + ((ksl * 4 + quad) * 64 + nt * 16 + mrow) * 8);
#pragma unroll
            for (int mtl = 0; mtl < 2; mtl++) {
                const int mt = wave * 2 + mtl;
                short8 ah = W3v[((mt * 8 + ks) * 2 + 0) * 64 + lane];
                short8 al = W3v[((mt * 8 + ks) * 2 + 1) * 64 + lane];
#pragma unroll
                for (int nt = 0; nt < 4; nt++) {
                    acc3[mtl][nt] = __builtin_amdgcn_mfma_f32_16x16x32_bf16(ah, bfr[nt], acc3[mtl][nt], 0, 0, 0);
                    acc3[mtl][nt] = __builtin_amdgcn_mfma_f32_16x16x32_bf16(al, bfr[nt], acc3[mtl][nt], 0, 0, 0);
                }
            }
        }
        __syncthreads();  // X3q reads done before next quarter overwrites
    }
    // ---- fused fc4 ----
    {
        float p4[4] = {0.f, 0.f, 0.f, 0.f};
#pragma unroll
        for (int mtl = 0; mtl < 2; mtl++) {
            const int mt = wave * 2 + mtl;
            const int n0 = mt * 16 + quad * 4;
            f32x4 b4 = *(const f32x4*)(fc3_b + n0);
            f32x4 w44 = *(const f32x4*)(fc4_w + n0);
#pragma unroll
            for (int nt = 0; nt < 4; nt++)
#pragma unroll
                for (int r = 0; r < 4; r++)
                    p4[nt] = fmaf(fmaxf(acc3[mtl][nt][r] + b4[r], 0.f), w44[r], p4[nt]);
        }
#pragma unroll
        for (int nt = 0; nt < 4; nt++) {
            p4[nt] += __shfl_xor(p4[nt], 16, 64);
            p4[nt] += __shfl_xor(p4[nt], 32, 64);
        }
        if (quad == 0) {
#pragma unroll
            for (int nt = 0; nt < 4; nt++)
                part[wave * 64 + nt * 16 + mrow] = p4[nt];
        }
    }
    __syncthreads();
    if (tid < 64) {
        float pred = part[tid] + part[64 + tid] + part[128 + tid] + part[192 + tid] + fc4_b[0];
        preds[p * 256 + e0 + tid] = pred;
    }
}

// ---------------- Kernel 2: propagation, one WAVE per pair (256 blocks) + fused normalize ----------------
__global__ __launch_bounds__(256)
void prop_norm(const int* __restrict__ edges, const float* __restrict__ preds,
               float* __restrict__ rbc_part, int* __restrict__ counter,
               float* __restrict__ out) {
    const int tid = threadIdx.x;
    const int wave = tid >> 6, lane = tid & 63;
    const int p = blockIdx.x * 4 + wave;
    const int s = p >> 5, t = p & 31;
    __shared__ float xw[4][32], xnw[4][32], raccw[4][32];
    __shared__ float red[8][32];
    __shared__ int lastflag;
    int u[4], v[4];
    float pr[4];
#pragma unroll
    for (int j = 0; j < 4; j++) {
        int e = lane + 64 * j;
        u[j] = edges[2 * e];
        v[j] = edges[2 * e + 1];
        pr[j] = preds[p * 256 + e];
    }
    if (lane < 32) { xw[wave][lane] = (lane == s) ? 1.f : 0.f; raccw[wave][lane] = 0.f; }
    const bool active = (s != t);
    for (int step = 0; step < 3; step++) {
        if (lane < 32) xnw[wave][lane] = 0.f;
        __syncthreads();
        if (active) {
#pragma unroll
            for (int j = 0; j < 4; j++)
                atomicAdd(&xnw[wave][v[j]], xw[wave][u[j]] * pr[j]);
        }
        __syncthreads();
        if (lane < 32) { raccw[wave][lane] += xnw[wave][lane]; xw[wave][lane] = xnw[wave][lane]; }
        __syncthreads();
    }
    if (active && lane < 32) atomicAdd(&rbc_part[(p & 63) * 32 + lane], raccw[wave][lane]);
    __syncthreads();  // drains rbc_part atomics before counter bump
    if (tid == 0) lastflag = (atomicAdd(counter, 1) == 255);
    __syncthreads();
    if (!lastflag) return;
    const int node = tid & 31, sub = tid >> 5;
    float vv = 0.f;
#pragma unroll
    for (int g = 0; g < 8; g++)
        vv += atomicAdd(&rbc_part[(sub * 8 + g) * 32 + node], 0.f);  // coherent read
    red[sub][node] = vv;
    __syncthreads();
    if (tid < 32) {
        float acc = 0.f;
#pragma unroll
        for (int sb = 0; sb < 8; sb++) acc += red[sb][tid];
        float tot = acc;
#pragma unroll
        for (int mask = 1; mask < 32; mask <<= 1) tot += __shfl_xor(tot, mask, 32);
        out[tid] = acc / tot;
    }
}

extern "C" void kernel_launch(void* const* d_in, const int* in_sizes, int n_in,
                              void* d_out, int out_size, void* d_ws, size_t ws_size,
                              hipStream_t stream) {
    const float* emb = (const float*)d_in[0];
    const int* edges = (const int*)d_in[1];
    const float* w1 = (const float*)d_in[2];
    const float* b1 = (const float*)d_in[3];
    const float* w2 = (const float*)d_in[4];
    const float* b2 = (const float*)d_in[5];
    const float* w3 = (const float*)d_in[6];
    const float* b3 = (const float*)d_in[7];
    const float* fc1_w = (const float*)d_in[8];
    const float* fc1_b = (const float*)d_in[9];
    const float* fc2_w = (const float*)d_in[10];
    const float* fc2_b = (const float*)d_in[11];
    const float* fc3_w = (const float*)d_in[12];
    const float* fc3_b = (const float*)d_in[13];
    const float* fc4_w = (const float*)d_in[14];
    const float* fc4_b = (const float*)d_in[15];

    float* ws = (float*)d_ws;
    float* F = ws;
    float* preds = ws + PREDS_OFF;
    float* rbc_part = ws + RBCP_OFF;
    int* counter = (int*)(ws + CNT_OFF);
    unsigned short* W1p = (unsigned short*)(ws + W1P_OFF);
    unsigned short* W2p = (unsigned short*)(ws + W2P_OFF);
    unsigned short* W3p = (unsigned short*)(ws + W3P_OFF);
    float* out = (float*)d_out;

    prep_all<<<dim3(641), dim3(256), 0, stream>>>(emb, w1, fc1_w, fc2_w, fc3_w,
                                                  F, W1p, W2p, W3p, rbc_part);
    mlp_kernel<<<dim3(4096), dim3(256), 0, stream>>>(
        F, edges, b1, w2, b2, w3, b3, fc1_b, fc2_b, fc3_b,
        fc4_w, fc4_b, W1p, W2p, W3p, preds);
    prop_norm<<<dim3(256), dim3(256), 0, stream>>>(edges, preds, rbc_part, counter, out);
}

// Round 14
// 202.459 us; speedup vs baseline: 1.1612x; 1.1612x over previous
//
#include <hip/hip_runtime.h>

// ---- ws layout (float offsets) ----
constexpr int F_ELEMS = 4 * 32 * 4 * 48;            // padded-48 conv1 tables
constexpr int PREDS_OFF = F_ELEMS;                  // 24576
constexpr int RBCP_OFF = PREDS_OFF + 1024 * 256;    // rbc_part[64][32]
constexpr int CNT_OFF = RBCP_OFF + 2048;            // completion counter (+pad)
constexpr int W1P_OFF = CNT_OFF + 16;               // fc1 A-frags: 8192 shorts
constexpr int W2P_OFF = W1P_OFF + 4096;             // fc2 A-frags: 65536 shorts
constexpr int W3P_OFF = W2P_OFF + 32768;            // fc3 A-frags: 65536 shorts

typedef __attribute__((ext_vector_type(8))) short short8;
typedef __attribute__((ext_vector_type(4))) short short4v;
typedef __attribute__((ext_vector_type(4))) float f32x4;

__device__ __forceinline__ unsigned short f2bf(float x) {  // RNE bf16
    unsigned u = __float_as_uint(x);
    u += 0x7FFF + ((u >> 16) & 1);
    return (unsigned short)(u >> 16);
}
__device__ __forceinline__ float bf2f(unsigned short h) {
    return __uint_as_float(((unsigned)h) << 16);
}

// ---------------- Kernel 0: all preprocessing (r9-verified) ----------------
__global__ void prep_all(const float* __restrict__ emb, const float* __restrict__ w1,
                         const float* __restrict__ fc1_w, const float* __restrict__ fc2_w,
                         const float* __restrict__ fc3_w,
                         float* __restrict__ F, unsigned short* __restrict__ W1p,
                         unsigned short* __restrict__ W2p, unsigned short* __restrict__ W3p,
                         float* __restrict__ rbcp_zero) {
    int b = blockIdx.x;
    if (b < 96) {
        int idx = b * 256 + threadIdx.x;  // 24576
        int i = idx % 48;
        int o = (idx / 48) % 4;
        int node = (idx / 192) % 32;
        int c = idx / 6144;
        float acc = 0.f;
        if (i < 46) {
#pragma unroll
            for (int k = 0; k < 3; k++) acc += w1[(o * 4 + c) * 3 + k] * emb[node * 96 + 2 * i + k];
        }
        F[idx] = acc;
        return;
    }
    if (b < 128) {  // fc1 A-layout, K padded 16->32
        int t = (b - 96) * 256 + threadIdx.x;  // 8192
        int j = t & 7, lane = (t >> 3) & 63, term = (t >> 9) & 1, mt = t >> 10;
        int k = (lane >> 4) * 8 + j, n = mt * 16 + (lane & 15);
        float w = (k < 16) ? fc1_w[k * 128 + n] : 0.f;
        unsigned short hi = f2bf(w);
        W1p[t] = (term == 0) ? hi : f2bf(w - bf2f(hi));
        return;
    }
    if (b < 384) {  // fc2 A-layout [16mt][4ks][2term]
        int t = (b - 128) * 256 + threadIdx.x;  // 65536
        int j = t & 7, lane = (t >> 3) & 63, term = (t >> 9) & 1, ks = (t >> 10) & 3, mt = t >> 12;
        int k = ks * 32 + (lane >> 4) * 8 + j, n = mt * 16 + (lane & 15);
        float w = fc2_w[k * 256 + n];
        unsigned short hi = f2bf(w);
        W2p[t] = (term == 0) ? hi : f2bf(w - bf2f(hi));
        return;
    }
    if (b < 640) {  // fc3 A-layout [8mt][8ks][2term]
        int t = (b - 384) * 256 + threadIdx.x;  // 65536
        int j = t & 7, lane = (t >> 3) & 63, term = (t >> 9) & 1, ks = (t >> 10) & 7, mt = t >> 13;
        int k = ks * 32 + (lane >> 4) * 8 + j, n = mt * 16 + (lane & 15);
        float w = fc3_w[k * 128 + n];
        unsigned short hi = f2bf(w);
        W3p[t] = (term == 0) ? hi : f2bf(w - bf2f(hi));
        return;
    }
    for (int k = threadIdx.x; k < 2064; k += 256) rbcp_zero[k] = 0.f;  // rbc_part + counter
}

// ---------------- Kernel 1: mlp, grid 4096, ONE 64-sample set per block. fc2->fc3 in FOUR
// 64-wide quarters through 8 KB X3q (LDS 25600 B -> 6 blocks/CU, LDS-limited).
// __launch_bounds__(256,4): r12's (256,6) clamped VGPRs (64->40) and spilled 283 MB to
// scratch. (256,4) compiles to 64 VGPR (8 waves/SIMD capable) with zero spill; occupancy
// is then LDS-limited at 6 blocks/CU. DO NOT raise the min-waves arg. r10 lesson: no
// multi-chunk loop either (also spills). ----------------
__global__ __launch_bounds__(256, 4)
void mlp_kernel(const float* __restrict__ F, const int* __restrict__ edges,
                const float* __restrict__ b1v,
                const float* __restrict__ w2, const float* __restrict__ b2,
                const float* __restrict__ w3, const float* __restrict__ b3,
                const float* __restrict__ fc1_b, const float* __restrict__ fc2_b,
                const float* __restrict__ fc3_b,
                const float* __restrict__ fc4_w, const float* __restrict__ fc4_b,
                const unsigned short* __restrict__ W1p, const unsigned short* __restrict__ W2p,
                const unsigned short* __restrict__ W3p,
                float* __restrict__ preds) {
    // LDS (floats): [0,2048) X3q region ([8g][64][8] shorts = 8 KB); X1 (4 KB) aliases its head
    //               [2048,6144) X2 bf16 [16g][64][8] (16 KB)
    //               [6144,6400) part[256]
    __shared__ __align__(16) float smem[6400];
    unsigned short* X1 = (unsigned short*)smem;
    unsigned short* X3q = (unsigned short*)smem;
    unsigned short* X2 = (unsigned short*)(smem + 2048);
    float* part = smem + 6144;

    const int tid = threadIdx.x;
    const int p = blockIdx.x >> 2;
    const int e0 = (blockIdx.x & 3) * 64;
    const int s = p >> 5, t = p & 31;
    if (s == t) return;

    const int gsample = tid >> 2, o = tid & 3;  // conv roles
    float h1[23];
    // ---- conv1: table sum (float4 loads, padded-48 rows) + pool -> regs ----
    {
        const int e = e0 + gsample;
        const int u = edges[2 * e], v = edges[2 * e + 1];
        const f32x4* F0 = (const f32x4*)(F + ((0 * 32 + s) * 4 + o) * 48);
        const f32x4* F1 = (const f32x4*)(F + ((1 * 32 + t) * 4 + o) * 48);
        const f32x4* F2 = (const f32x4*)(F + ((2 * 32 + u) * 4 + o) * 48);
        const f32x4* F3 = (const f32x4*)(F + ((3 * 32 + v) * 4 + o) * 48);
        const float bb = b1v[o];
        float pre[46];
#pragma unroll
        for (int q = 0; q < 12; q++) {
            f32x4 x = F0[q] + F1[q] + F2[q] + F3[q];
#pragma unroll
            for (int z = 0; z < 4; z++) {
                int i = 4 * q + z;
                if (i < 46) pre[i] = fmaxf(x[z] + bb, 0.f);
            }
        }
#pragma unroll
        for (int j = 0; j < 23; j++) h1[j] = fmaxf(pre[2 * j], pre[2 * j + 1]);
    }
    float h2[10];
    // ---- conv2: cross-channel via shfl_xor (4-lane groups), sliding ring ----
    {
        float wm[4][3];
#pragma unroll
        for (int m = 0; m < 4; m++)
#pragma unroll
            for (int k = 0; k < 3; k++) wm[m][k] = w2[o * 12 + (o ^ m) * 3 + k];
        const float bb = b2[o];
        float win[4][3];
#pragma unroll
        for (int j = 0; j < 2; j++) {
            float x = h1[j];
            win[0][j] = x;
            win[1][j] = __shfl_xor(x, 1, 64);
            win[2][j] = __shfl_xor(x, 2, 64);
            win[3][j] = __shfl_xor(x, 3, 64);
        }
        float pre[20];
#pragma unroll
        for (int i = 0; i < 20; i++) {
            float x = h1[i + 2];
            win[0][(i + 2) % 3] = x;
            win[1][(i + 2) % 3] = __shfl_xor(x, 1, 64);
            win[2][(i + 2) % 3] = __shfl_xor(x, 2, 64);
            win[3][(i + 2) % 3] = __shfl_xor(x, 3, 64);
            float acc = bb;
#pragma unroll
            for (int m = 0; m < 4; m++)
#pragma unroll
                for (int k = 0; k < 3; k++)
                    acc = fmaf(wm[m][k], win[m][(i + k) % 3], acc);
            pre[i] = fmaxf(acc, 0.f);
        }
#pragma unroll
        for (int j = 0; j < 10; j++) h2[j] = fmaxf(pre[2 * j], pre[2 * j + 1]);
    }
    // ---- conv3 + pool -> X1 (bf16 B-frag layout, K 16 padded to 32) ----
    {
        float wm[4][3];
#pragma unroll
        for (int m = 0; m < 4; m++)
#pragma unroll
            for (int k = 0; k < 3; k++) wm[m][k] = w3[o * 12 + (o ^ m) * 3 + k];
        const float bb = b3[o];
        float win[4][3];
#pragma unroll
        for (int j = 0; j < 2; j++) {
            float x = h2[j];
            win[0][j] = x;
            win[1][j] = __shfl_xor(x, 1, 64);
            win[2][j] = __shfl_xor(x, 2, 64);
            win[3][j] = __shfl_xor(x, 3, 64);
        }
        float pre[8];
#pragma unroll
        for (int i = 0; i < 8; i++) {
            float x = h2[i + 2];
            win[0][(i + 2) % 3] = x;
            win[1][(i + 2) % 3] = __shfl_xor(x, 1, 64);
            win[2][(i + 2) % 3] = __shfl_xor(x, 2, 64);
            win[3][(i + 2) % 3] = __shfl_xor(x, 3, 64);
            float acc = bb;
#pragma unroll
            for (int m = 0; m < 4; m++)
#pragma unroll
                for (int k = 0; k < 3; k++)
                    acc = fmaf(wm[m][k], win[m][(i + k) % 3], acc);
            pre[i] = fmaxf(acc, 0.f);
        }
        short4v pk;
#pragma unroll
        for (int l = 0; l < 4; l++)
            pk[l] = (short)f2bf(fmaxf(pre[2 * l], pre[2 * l + 1]));
        *(short4v*)(X1 + (((o >> 1) * 64 + gsample) * 8) + (o & 1) * 4) = pk;
        short4v z4 = (short4v){0, 0, 0, 0};
        *(short4v*)(X1 + ((((o >> 1) + 2) * 64 + gsample) * 8) + (o & 1) * 4) = z4;
    }
    __syncthreads();  // barrier 1: X1 visible
    const int lane = tid & 63, wave = tid >> 6;
    const int mrow = lane & 15, quad = lane >> 4;
    // ---- fc1 MFMA ----
    {
        const short8* W1v = (const short8*)W1p;
        short8 bnt[4];
#pragma unroll
        for (int nt = 0; nt < 4; nt++)
            bnt[nt] = *(const short8*)(X1 + (quad * 64 + nt * 16 + mrow) * 8);
        f32x4 acc1[2][4];
#pragma unroll
        for (int a = 0; a < 2; a++)
#pragma unroll
            for (int b = 0; b < 4; b++) acc1[a][b] = (f32x4){0.f, 0.f, 0.f, 0.f};
#pragma unroll
        for (int mtl = 0; mtl < 2; mtl++) {
            const int mt = wave * 2 + mtl;
            short8 ah = W1v[(mt * 2 + 0) * 64 + lane];
            short8 al = W1v[(mt * 2 + 1) * 64 + lane];
#pragma unroll
            for (int nt = 0; nt < 4; nt++) {
                acc1[mtl][nt] = __builtin_amdgcn_mfma_f32_16x16x32_bf16(ah, bnt[nt], acc1[mtl][nt], 0, 0, 0);
                acc1[mtl][nt] = __builtin_amdgcn_mfma_f32_16x16x32_bf16(al, bnt[nt], acc1[mtl][nt], 0, 0, 0);
            }
        }
#pragma unroll
        for (int mtl = 0; mtl < 2; mtl++) {
            const int mt = wave * 2 + mtl;
            const int n0 = mt * 16 + quad * 4;
            f32x4 b4 = *(const f32x4*)(fc1_b + n0);
#pragma unroll
            for (int nt = 0; nt < 4; nt++) {
                short4v pk;
#pragma unroll
                for (int r = 0; r < 4; r++)
                    pk[r] = (short)f2bf(fmaxf(acc1[mtl][nt][r] + b4[r], 0.f));
                *(short4v*)(X2 + ((n0 >> 3) * 64 + nt * 16 + mrow) * 8 + (n0 & 7)) = pk;
            }
        }
    }
    __syncthreads();  // barrier 2: X2 ready, X1 reads done (X3q writes may follow)
    // ---- fc2 -> fc3 in FOUR 64-output quarters through X3q ----
    const short8* W2v = (const short8*)W2p;
    const short8* W3v = (const short8*)W3p;
    f32x4 acc3[2][4];
#pragma unroll
    for (int a = 0; a < 2; a++)
#pragma unroll
        for (int b = 0; b < 4; b++) acc3[a][b] = (f32x4){0.f, 0.f, 0.f, 0.f};
#pragma unroll
    for (int q = 0; q < 4; q++) {
        // fc2 quarter: wave owns mt = q*4 + wave (one 16-output tile), full K=128 from X2
        const int mt2 = q * 4 + wave;
        f32x4 acc2[4];
#pragma unroll
        for (int b = 0; b < 4; b++) acc2[b] = (f32x4){0.f, 0.f, 0.f, 0.f};
#pragma unroll
        for (int ks = 0; ks < 4; ks++) {
            short8 bfr[4];
#pragma unroll
            for (int nt = 0; nt < 4; nt++)
                bfr[nt] = *(const short8*)(X2 + ((ks * 4 + quad) * 64 + nt * 16 + mrow) * 8);
            short8 ah = W2v[((mt2 * 4 + ks) * 2 + 0) * 64 + lane];
            short8 al = W2v[((mt2 * 4 + ks) * 2 + 1) * 64 + lane];
#pragma unroll
            for (int nt = 0; nt < 4; nt++) {
                acc2[nt] = __builtin_amdgcn_mfma_f32_16x16x32_bf16(ah, bfr[nt], acc2[nt], 0, 0, 0);
                acc2[nt] = __builtin_amdgcn_mfma_f32_16x16x32_bf16(al, bfr[nt], acc2[nt], 0, 0, 0);
            }
        }
        // epilogue -> X3q (k-local = n - q*64, in [0,64))
        {
            const int n0 = mt2 * 16 + quad * 4;
            const int kl = n0 - q * 64;
            f32x4 b4 = *(const f32x4*)(fc2_b + n0);
#pragma unroll
            for (int nt = 0; nt < 4; nt++) {
                short4v pk;
#pragma unroll
                for (int r = 0; r < 4; r++)
                    pk[r] = (short)f2bf(fmaxf(acc2[nt][r] + b4[r], 0.f));
                *(short4v*)(X3q + ((kl >> 3) * 64 + nt * 16 + mrow) * 8 + (kl & 7)) = pk;
            }
        }
        __syncthreads();  // X3q quarter ready
        // fc3 accumulate this quarter's 2 ks-groups (global ks = q*2+ksl)
#pragma unroll
        for (int ksl = 0; ksl < 2; ksl++) {
            const int ks = q * 2 + ksl;
            short8 bfr[4];
#pragma unroll
            for (int nt = 0; nt < 4; nt++)
                bfr[nt] = *(const short8*)(X3q + ((ksl * 4 + quad) * 64 + nt * 16 + mrow) * 8);
#pragma unroll
            for (int mtl = 0; mtl < 2; mtl++) {
                const int mt = wave * 2 + mtl;
                short8 ah = W3v[((mt * 8 + ks) * 2 + 0) * 64 + lane];
                short8 al = W3v[((mt * 8 + ks) * 2 + 1) * 64 + lane];
#pragma unroll
                for (int nt = 0; nt < 4; nt++) {
                    acc3[mtl][nt] = __builtin_amdgcn_mfma_f32_16x16x32_bf16(ah, bfr[nt], acc3[mtl][nt], 0, 0, 0);
                    acc3[mtl][nt] = __builtin_amdgcn_mfma_f32_16x16x32_bf16(al, bfr[nt], acc3[mtl][nt], 0, 0, 0);
                }
            }
        }
        __syncthreads();  // X3q reads done before next quarter overwrites
    }
    // ---- fused fc4 ----
    {
        float p4[4] = {0.f, 0.f, 0.f, 0.f};
#pragma unroll
        for (int mtl = 0; mtl < 2; mtl++) {
            const int mt = wave * 2 + mtl;
            const int n0 = mt * 16 + quad * 4;
            f32x4 b4 = *(const f32x4*)(fc3_b + n0);
            f32x4 w44 = *(const f32x4*)(fc4_w + n0);
#pragma unroll
            for (int nt = 0; nt < 4; nt++)
#pragma unroll
                for (int r = 0; r < 4; r++)
                    p4[nt] = fmaf(fmaxf(acc3[mtl][nt][r] + b4[r], 0.f), w44[r], p4[nt]);
        }
#pragma unroll
        for (int nt = 0; nt < 4; nt++) {
            p4[nt] += __shfl_xor(p4[nt], 16, 64);
            p4[nt] += __shfl_xor(p4[nt], 32, 64);
        }
        if (quad == 0) {
#pragma unroll
            for (int nt = 0; nt < 4; nt++)
                part[wave * 64 + nt * 16 + mrow] = p4[nt];
        }
    }
    __syncthreads();
    if (tid < 64) {
        float pred = part[tid] + part[64 + tid] + part[128 + tid] + part[192 + tid] + fc4_b[0];
        preds[p * 256 + e0 + tid] = pred;
    }
}

// ---------------- Kernel 2: propagation, one WAVE per pair (256 blocks) + fused normalize ----------------
__global__ __launch_bounds__(256)
void prop_norm(const int* __restrict__ edges, const float* __restrict__ preds,
               float* __restrict__ rbc_part, int* __restrict__ counter,
               float* __restrict__ out) {
    const int tid = threadIdx.x;
    const int wave = tid >> 6, lane = tid & 63;
    const int p = blockIdx.x * 4 + wave;
    const int s = p >> 5, t = p & 31;
    __shared__ float xw[4][32], xnw[4][32], raccw[4][32];
    __shared__ float red[8][32];
    __shared__ int lastflag;
    int u[4], v[4];
    float pr[4];
#pragma unroll
    for (int j = 0; j < 4; j++) {
        int e = lane + 64 * j;
        u[j] = edges[2 * e];
        v[j] = edges[2 * e + 1];
        pr[j] = preds[p * 256 + e];
    }
    if (lane < 32) { xw[wave][lane] = (lane == s) ? 1.f : 0.f; raccw[wave][lane] = 0.f; }
    const bool active = (s != t);
    for (int step = 0; step < 3; step++) {
        if (lane < 32) xnw[wave][lane] = 0.f;
        __syncthreads();
        if (active) {
#pragma unroll
            for (int j = 0; j < 4; j++)
                atomicAdd(&xnw[wave][v[j]], xw[wave][u[j]] * pr[j]);
        }
        __syncthreads();
        if (lane < 32) { raccw[wave][lane] += xnw[wave][lane]; xw[wave][lane] = xnw[wave][lane]; }
        __syncthreads();
    }
    if (active && lane < 32) atomicAdd(&rbc_part[(p & 63) * 32 + lane], raccw[wave][lane]);
    __syncthreads();  // drains rbc_part atomics before counter bump
    if (tid == 0) lastflag = (atomicAdd(counter, 1) == 255);
    __syncthreads();
    if (!lastflag) return;
    const int node = tid & 31, sub = tid >> 5;
    float vv = 0.f;
#pragma unroll
    for (int g = 0; g < 8; g++)
        vv += atomicAdd(&rbc_part[(sub * 8 + g) * 32 + node], 0.f);  // coherent read
    red[sub][node] = vv;
    __syncthreads();
    if (tid < 32) {
        float acc = 0.f;
#pragma unroll
        for (int sb = 0; sb < 8; sb++) acc += red[sb][tid];
        float tot = acc;
#pragma unroll
        for (int mask = 1; mask < 32; mask <<= 1) tot += __shfl_xor(tot, mask, 32);
        out[tid] = acc / tot;
    }
}

extern "C" void kernel_launch(void* const* d_in, const int* in_sizes, int n_in,
                              void* d_out, int out_size, void* d_ws, size_t ws_size,
                              hipStream_t stream) {
    const float* emb = (const float*)d_in[0];
    const int* edges = (const int*)d_in[1];
    const float* w1 = (const float*)d_in[2];
    const float* b1 = (const float*)d_in[3];
    const float* w2 = (const float*)d_in[4];
    const float* b2 = (const float*)d_in[5];
    const float* w3 = (const float*)d_in[6];
    const float* b3 = (const float*)d_in[7];
    const float* fc1_w = (const float*)d_in[8];
    const float* fc1_b = (const float*)d_in[9];
    const float* fc2_w = (const float*)d_in[10];
    const float* fc2_b = (const float*)d_in[11];
    const float* fc3_w = (const float*)d_in[12];
    const float* fc3_b = (const float*)d_in[13];
    const float* fc4_w = (const float*)d_in[14];
    const float* fc4_b = (const float*)d_in[15];

    float* ws = (float*)d_ws;
    float* F = ws;
    float* preds = ws + PREDS_OFF;
    float* rbc_part = ws + RBCP_OFF;
    int* counter = (int*)(ws + CNT_OFF);
    unsigned short* W1p = (unsigned short*)(ws + W1P_OFF);
    unsigned short* W2p = (unsigned short*)(ws + W2P_OFF);
    unsigned short* W3p = (unsigned short*)(ws + W3P_OFF);
    float* out = (float*)d_out;

    prep_all<<<dim3(641), dim3(256), 0, stream>>>(emb, w1, fc1_w, fc2_w, fc3_w,
                                                  F, W1p, W2p, W3p, rbc_part);
    mlp_kernel<<<dim3(4096), dim3(256), 0, stream>>>(
        F, edges, b1, w2, b2, w3, b3, fc1_b, fc2_b, fc3_b,
        fc4_w, fc4_b, W1p, W2p, W3p, preds);
    prop_norm<<<dim3(256), dim3(256), 0, stream>>>(edges, preds, rbc_part, counter, out);
}

// Round 15
// 188.077 us; speedup vs baseline: 1.2500x; 1.0765x over previous
//
#include <hip/hip_runtime.h>

// ---- ws layout (float offsets) ----
constexpr int F_ELEMS = 4 * 32 * 4 * 48;            // padded-48 conv1 tables
constexpr int PREDS_OFF = F_ELEMS;                  // 24576
constexpr int RBCP_OFF = PREDS_OFF + 1024 * 256;    // rbc_part[64][32]
constexpr int CNT_OFF = RBCP_OFF + 2048;            // completion counter (+pad)
constexpr int W1P_OFF = CNT_OFF + 16;               // fc1 A-frags: 8192 shorts
constexpr int W2P_OFF = W1P_OFF + 4096;             // fc2 A-frags: 65536 shorts
constexpr int W3P_OFF = W2P_OFF + 32768;            // fc3 A-frags: 65536 shorts

typedef __attribute__((ext_vector_type(8))) short short8;
typedef __attribute__((ext_vector_type(4))) short short4v;
typedef __attribute__((ext_vector_type(4))) float f32x4;

__device__ __forceinline__ unsigned short f2bf(float x) {  // RNE bf16
    unsigned u = __float_as_uint(x);
    u += 0x7FFF + ((u >> 16) & 1);
    return (unsigned short)(u >> 16);
}
__device__ __forceinline__ float bf2f(unsigned short h) {
    return __uint_as_float(((unsigned)h) << 16);
}

// ---------------- Kernel 0: all preprocessing (r9-verified) ----------------
__global__ void prep_all(const float* __restrict__ emb, const float* __restrict__ w1,
                         const float* __restrict__ fc1_w, const float* __restrict__ fc2_w,
                         const float* __restrict__ fc3_w,
                         float* __restrict__ F, unsigned short* __restrict__ W1p,
                         unsigned short* __restrict__ W2p, unsigned short* __restrict__ W3p,
                         float* __restrict__ rbcp_zero) {
    int b = blockIdx.x;
    if (b < 96) {
        int idx = b * 256 + threadIdx.x;  // 24576
        int i = idx % 48;
        int o = (idx / 48) % 4;
        int node = (idx / 192) % 32;
        int c = idx / 6144;
        float acc = 0.f;
        if (i < 46) {
#pragma unroll
            for (int k = 0; k < 3; k++) acc += w1[(o * 4 + c) * 3 + k] * emb[node * 96 + 2 * i + k];
        }
        F[idx] = acc;
        return;
    }
    if (b < 128) {  // fc1 A-layout, K padded 16->32
        int t = (b - 96) * 256 + threadIdx.x;  // 8192
        int j = t & 7, lane = (t >> 3) & 63, term = (t >> 9) & 1, mt = t >> 10;
        int k = (lane >> 4) * 8 + j, n = mt * 16 + (lane & 15);
        float w = (k < 16) ? fc1_w[k * 128 + n] : 0.f;
        unsigned short hi = f2bf(w);
        W1p[t] = (term == 0) ? hi : f2bf(w - bf2f(hi));
        return;
    }
    if (b < 384) {  // fc2 A-layout [16mt][4ks][2term]
        int t = (b - 128) * 256 + threadIdx.x;  // 65536
        int j = t & 7, lane = (t >> 3) & 63, term = (t >> 9) & 1, ks = (t >> 10) & 3, mt = t >> 12;
        int k = ks * 32 + (lane >> 4) * 8 + j, n = mt * 16 + (lane & 15);
        float w = fc2_w[k * 256 + n];
        unsigned short hi = f2bf(w);
        W2p[t] = (term == 0) ? hi : f2bf(w - bf2f(hi));
        return;
    }
    if (b < 640) {  // fc3 A-layout [8mt][8ks][2term]
        int t = (b - 384) * 256 + threadIdx.x;  // 65536
        int j = t & 7, lane = (t >> 3) & 63, term = (t >> 9) & 1, ks = (t >> 10) & 7, mt = t >> 13;
        int k = ks * 32 + (lane >> 4) * 8 + j, n = mt * 16 + (lane & 15);
        float w = fc3_w[k * 128 + n];
        unsigned short hi = f2bf(w);
        W3p[t] = (term == 0) ? hi : f2bf(w - bf2f(hi));
        return;
    }
    for (int k = threadIdx.x; k < 2064; k += 256) rbcp_zero[k] = 0.f;  // rbc_part + counter
}

// ---------------- Kernel 1: r11-verified mlp (best: 110.8 us). grid 4096, ONE 64-sample set
// per block; shfl-conv; fc2->fc3 in TWO K=128 halves through 16 KB X3h; LDS 33792 B ->
// 4 blocks/CU. Established dead ends (do not retry): multi-chunk loop (r10: spills, 431 MB),
// min-waves=6 bound (r12: VGPR clamp 40, spills), 64-wide quarters (r14: occupancy flat at
// 38%, +13 us), fused prop via counters (r8: +19 us), one-block-per-pair (r10). ----------------
__global__ __launch_bounds__(256, 4)
void mlp_kernel(const float* __restrict__ F, const int* __restrict__ edges,
                const float* __restrict__ b1v,
                const float* __restrict__ w2, const float* __restrict__ b2,
                const float* __restrict__ w3, const float* __restrict__ b3,
                const float* __restrict__ fc1_b, const float* __restrict__ fc2_b,
                const float* __restrict__ fc3_b,
                const float* __restrict__ fc4_w, const float* __restrict__ fc4_b,
                const unsigned short* __restrict__ W1p, const unsigned short* __restrict__ W2p,
                const unsigned short* __restrict__ W3p,
                float* __restrict__ preds) {
    // LDS (floats): [0,4096) X3-half region, X1 aliases its head ([4g][64][8] shorts = 4 KB)
    //               [4096,8192) X2 bf16 [16g][64][8]
    //               [8192,8448) part[256]
    __shared__ __align__(16) float smem[8448];
    unsigned short* X1 = (unsigned short*)smem;
    unsigned short* X3h = (unsigned short*)smem;
    unsigned short* X2 = (unsigned short*)(smem + 4096);
    float* part = smem + 8192;

    const int tid = threadIdx.x;
    const int p = blockIdx.x >> 2;
    const int e0 = (blockIdx.x & 3) * 64;
    const int s = p >> 5, t = p & 31;
    if (s == t) return;

    const int gsample = tid >> 2, o = tid & 3;  // conv roles
    float h1[23];
    // ---- conv1: table sum (float4 loads, padded-48 rows) + pool -> regs ----
    {
        const int e = e0 + gsample;
        const int u = edges[2 * e], v = edges[2 * e + 1];
        const f32x4* F0 = (const f32x4*)(F + ((0 * 32 + s) * 4 + o) * 48);
        const f32x4* F1 = (const f32x4*)(F + ((1 * 32 + t) * 4 + o) * 48);
        const f32x4* F2 = (const f32x4*)(F + ((2 * 32 + u) * 4 + o) * 48);
        const f32x4* F3 = (const f32x4*)(F + ((3 * 32 + v) * 4 + o) * 48);
        const float bb = b1v[o];
        float pre[46];
#pragma unroll
        for (int q = 0; q < 12; q++) {
            f32x4 x = F0[q] + F1[q] + F2[q] + F3[q];
#pragma unroll
            for (int z = 0; z < 4; z++) {
                int i = 4 * q + z;
                if (i < 46) pre[i] = fmaxf(x[z] + bb, 0.f);
            }
        }
#pragma unroll
        for (int j = 0; j < 23; j++) h1[j] = fmaxf(pre[2 * j], pre[2 * j + 1]);
    }
    float h2[10];
    // ---- conv2: cross-channel via shfl_xor (4-lane groups), sliding ring ----
    {
        float wm[4][3];  // wm[m][k] = w2[o][o^m][k]
#pragma unroll
        for (int m = 0; m < 4; m++)
#pragma unroll
            for (int k = 0; k < 3; k++) wm[m][k] = w2[o * 12 + (o ^ m) * 3 + k];
        const float bb = b2[o];
        float win[4][3];
#pragma unroll
        for (int j = 0; j < 2; j++) {
            float x = h1[j];
            win[0][j] = x;
            win[1][j] = __shfl_xor(x, 1, 64);
            win[2][j] = __shfl_xor(x, 2, 64);
            win[3][j] = __shfl_xor(x, 3, 64);
        }
        float pre[20];
#pragma unroll
        for (int i = 0; i < 20; i++) {
            float x = h1[i + 2];
            win[0][(i + 2) % 3] = x;
            win[1][(i + 2) % 3] = __shfl_xor(x, 1, 64);
            win[2][(i + 2) % 3] = __shfl_xor(x, 2, 64);
            win[3][(i + 2) % 3] = __shfl_xor(x, 3, 64);
            float acc = bb;
#pragma unroll
            for (int m = 0; m < 4; m++)
#pragma unroll
                for (int k = 0; k < 3; k++)
                    acc = fmaf(wm[m][k], win[m][(i + k) % 3], acc);
            pre[i] = fmaxf(acc, 0.f);
        }
#pragma unroll
        for (int j = 0; j < 10; j++) h2[j] = fmaxf(pre[2 * j], pre[2 * j + 1]);
    }
    // ---- conv3 + pool -> X1 (bf16 B-frag layout, K 16 padded to 32) ----
    {
        float wm[4][3];
#pragma unroll
        for (int m = 0; m < 4; m++)
#pragma unroll
            for (int k = 0; k < 3; k++) wm[m][k] = w3[o * 12 + (o ^ m) * 3 + k];
        const float bb = b3[o];
        float win[4][3];
#pragma unroll
        for (int j = 0; j < 2; j++) {
            float x = h2[j];
            win[0][j] = x;
            win[1][j] = __shfl_xor(x, 1, 64);
            win[2][j] = __shfl_xor(x, 2, 64);
            win[3][j] = __shfl_xor(x, 3, 64);
        }
        float pre[8];
#pragma unroll
        for (int i = 0; i < 8; i++) {
            float x = h2[i + 2];
            win[0][(i + 2) % 3] = x;
            win[1][(i + 2) % 3] = __shfl_xor(x, 1, 64);
            win[2][(i + 2) % 3] = __shfl_xor(x, 2, 64);
            win[3][(i + 2) % 3] = __shfl_xor(x, 3, 64);
            float acc = bb;
#pragma unroll
            for (int m = 0; m < 4; m++)
#pragma unroll
                for (int k = 0; k < 3; k++)
                    acc = fmaf(wm[m][k], win[m][(i + k) % 3], acc);
            pre[i] = fmaxf(acc, 0.f);
        }
        short4v pk;
#pragma unroll
        for (int l = 0; l < 4; l++)
            pk[l] = (short)f2bf(fmaxf(pre[2 * l], pre[2 * l + 1]));
        // k = o*4+l -> g = o>>1, j = (o&1)*4+l
        *(short4v*)(X1 + (((o >> 1) * 64 + gsample) * 8) + (o & 1) * 4) = pk;
        short4v z4 = (short4v){0, 0, 0, 0};  // k in [16,32) zeros
        *(short4v*)(X1 + ((((o >> 1) + 2) * 64 + gsample) * 8) + (o & 1) * 4) = z4;
    }
    __syncthreads();  // barrier 1: X1 visible to all waves
    const int lane = tid & 63, wave = tid >> 6;
    const int mrow = lane & 15, quad = lane >> 4;
    // ---- fc1 MFMA: A=W1p (8 mt, wave owns 2), B=X1 ----
    {
        const short8* W1v = (const short8*)W1p;
        short8 bnt[4];
#pragma unroll
        for (int nt = 0; nt < 4; nt++)
            bnt[nt] = *(const short8*)(X1 + (quad * 64 + nt * 16 + mrow) * 8);
        f32x4 acc1[2][4];
#pragma unroll
        for (int a = 0; a < 2; a++)
#pragma unroll
            for (int b = 0; b < 4; b++) acc1[a][b] = (f32x4){0.f, 0.f, 0.f, 0.f};
#pragma unroll
        for (int mtl = 0; mtl < 2; mtl++) {
            const int mt = wave * 2 + mtl;
            short8 ah = W1v[(mt * 2 + 0) * 64 + lane];
            short8 al = W1v[(mt * 2 + 1) * 64 + lane];
#pragma unroll
            for (int nt = 0; nt < 4; nt++) {
                acc1[mtl][nt] = __builtin_amdgcn_mfma_f32_16x16x32_bf16(ah, bnt[nt], acc1[mtl][nt], 0, 0, 0);
                acc1[mtl][nt] = __builtin_amdgcn_mfma_f32_16x16x32_bf16(al, bnt[nt], acc1[mtl][nt], 0, 0, 0);
            }
        }
        // epilogue straight to X2 (disjoint region; no barrier needed)
#pragma unroll
        for (int mtl = 0; mtl < 2; mtl++) {
            const int mt = wave * 2 + mtl;
            const int n0 = mt * 16 + quad * 4;
            f32x4 b4 = *(const f32x4*)(fc1_b + n0);
#pragma unroll
            for (int nt = 0; nt < 4; nt++) {
                short4v pk;
#pragma unroll
                for (int r = 0; r < 4; r++)
                    pk[r] = (short)f2bf(fmaxf(acc1[mtl][nt][r] + b4[r], 0.f));
                *(short4v*)(X2 + ((n0 >> 3) * 64 + nt * 16 + mrow) * 8 + (n0 & 7)) = pk;
            }
        }
    }
    __syncthreads();  // barrier 2: X2 visible; X1 reads done (X3h writes may follow)
    // ---- fc2 -> fc3 in two K=128 halves through X3h ----
    const short8* W2v = (const short8*)W2p;
    const short8* W3v = (const short8*)W3p;
    f32x4 acc3[2][4];
#pragma unroll
    for (int a = 0; a < 2; a++)
#pragma unroll
        for (int b = 0; b < 4; b++) acc3[a][b] = (f32x4){0.f, 0.f, 0.f, 0.f};
#pragma unroll
    for (int h = 0; h < 2; h++) {
        // fc2 half: wave owns 2 of 8 mt in this half (full K=128 from X2)
        f32x4 acc2[2][4];
#pragma unroll
        for (int a = 0; a < 2; a++)
#pragma unroll
            for (int b = 0; b < 4; b++) acc2[a][b] = (f32x4){0.f, 0.f, 0.f, 0.f};
#pragma unroll
        for (int ks = 0; ks < 4; ks++) {
            short8 bfr[4];
#pragma unroll
            for (int nt = 0; nt < 4; nt++)
                bfr[nt] = *(const short8*)(X2 + ((ks * 4 + quad) * 64 + nt * 16 + mrow) * 8);
#pragma unroll
            for (int mtl = 0; mtl < 2; mtl++) {
                const int mt = h * 8 + wave * 2 + mtl;
                short8 ah = W2v[((mt * 4 + ks) * 2 + 0) * 64 + lane];
                short8 al = W2v[((mt * 4 + ks) * 2 + 1) * 64 + lane];
#pragma unroll
                for (int nt = 0; nt < 4; nt++) {
                    acc2[mtl][nt] = __builtin_amdgcn_mfma_f32_16x16x32_bf16(ah, bfr[nt], acc2[mtl][nt], 0, 0, 0);
                    acc2[mtl][nt] = __builtin_amdgcn_mfma_f32_16x16x32_bf16(al, bfr[nt], acc2[mtl][nt], 0, 0, 0);
                }
            }
        }
        // epilogue -> X3h (k-local = n - h*128)
#pragma unroll
        for (int mtl = 0; mtl < 2; mtl++) {
            const int mt = h * 8 + wave * 2 + mtl;
            const int n0 = mt * 16 + quad * 4;
            const int kl = n0 - h * 128;
            f32x4 b4 = *(const f32x4*)(fc2_b + n0);
#pragma unroll
            for (int nt = 0; nt < 4; nt++) {
                short4v pk;
#pragma unroll
                for (int r = 0; r < 4; r++)
                    pk[r] = (short)f2bf(fmaxf(acc2[mtl][nt][r] + b4[r], 0.f));
                *(short4v*)(X3h + ((kl >> 3) * 64 + nt * 16 + mrow) * 8 + (kl & 7)) = pk;
            }
        }
        __syncthreads();  // barrier 3/5: X3h half ready
        // fc3 accumulate this half's 4 ks
#pragma unroll
        for (int ksl = 0; ksl < 4; ksl++) {
            const int ks = h * 4 + ksl;
            short8 bfr[4];
#pragma unroll
            for (int nt = 0; nt < 4; nt++)
                bfr[nt] = *(const short8*)(X3h + ((ksl * 4 + quad) * 64 + nt * 16 + mrow) * 8);
#pragma unroll
            for (int mtl = 0; mtl < 2; mtl++) {
                const int mt = wave * 2 + mtl;
                short8 ah = W3v[((mt * 8 + ks) * 2 + 0) * 64 + lane];
                short8 al = W3v[((mt * 8 + ks) * 2 + 1) * 64 + lane];
#pragma unroll
                for (int nt = 0; nt < 4; nt++) {
                    acc3[mtl][nt] = __builtin_amdgcn_mfma_f32_16x16x32_bf16(ah, bfr[nt], acc3[mtl][nt], 0, 0, 0);
                    acc3[mtl][nt] = __builtin_amdgcn_mfma_f32_16x16x32_bf16(al, bfr[nt], acc3[mtl][nt], 0, 0, 0);
                }
            }
        }
        __syncthreads();  // barrier 4/6: X3h reads done before reuse / part writes
    }
    // ---- fused fc4 ----
    {
        float p4[4] = {0.f, 0.f, 0.f, 0.f};
#pragma unroll
        for (int mtl = 0; mtl < 2; mtl++) {
            const int mt = wave * 2 + mtl;
            const int n0 = mt * 16 + quad * 4;
            f32x4 b4 = *(const f32x4*)(fc3_b + n0);
            f32x4 w44 = *(const f32x4*)(fc4_w + n0);
#pragma unroll
            for (int nt = 0; nt < 4; nt++)
#pragma unroll
                for (int r = 0; r < 4; r++)
                    p4[nt] = fmaf(fmaxf(acc3[mtl][nt][r] + b4[r], 0.f), w44[r], p4[nt]);
        }
#pragma unroll
        for (int nt = 0; nt < 4; nt++) {
            p4[nt] += __shfl_xor(p4[nt], 16, 64);
            p4[nt] += __shfl_xor(p4[nt], 32, 64);
        }
        if (quad == 0) {
#pragma unroll
            for (int nt = 0; nt < 4; nt++)
                part[wave * 64 + nt * 16 + mrow] = p4[nt];
        }
    }
    __syncthreads();
    if (tid < 64) {
        float pred = part[tid] + part[64 + tid] + part[128 + tid] + part[192 + tid] + fc4_b[0];
        preds[p * 256 + e0 + tid] = pred;
    }
}

// ---------------- Kernel 2: propagation, one WAVE per pair (256 blocks) + fused normalize ----------------
__global__ __launch_bounds__(256)
void prop_norm(const int* __restrict__ edges, const float* __restrict__ preds,
               float* __restrict__ rbc_part, int* __restrict__ counter,
               float* __restrict__ out) {
    const int tid = threadIdx.x;
    const int wave = tid >> 6, lane = tid & 63;
    const int p = blockIdx.x * 4 + wave;
    const int s = p >> 5, t = p & 31;
    __shared__ float xw[4][32], xnw[4][32], raccw[4][32];
    __shared__ float red[8][32];
    __shared__ int lastflag;
    int u[4], v[4];
    float pr[4];
#pragma unroll
    for (int j = 0; j < 4; j++) {
        int e = lane + 64 * j;
        u[j] = edges[2 * e];
        v[j] = edges[2 * e + 1];
        pr[j] = preds[p * 256 + e];
    }
    if (lane < 32) { xw[wave][lane] = (lane == s) ? 1.f : 0.f; raccw[wave][lane] = 0.f; }
    const bool active = (s != t);
    for (int step = 0; step < 3; step++) {
        if (lane < 32) xnw[wave][lane] = 0.f;
        __syncthreads();
        if (active) {
#pragma unroll
            for (int j = 0; j < 4; j++)
                atomicAdd(&xnw[wave][v[j]], xw[wave][u[j]] * pr[j]);
        }
        __syncthreads();
        if (lane < 32) { raccw[wave][lane] += xnw[wave][lane]; xw[wave][lane] = xnw[wave][lane]; }
        __syncthreads();
    }
    if (active && lane < 32) atomicAdd(&rbc_part[(p & 63) * 32 + lane], raccw[wave][lane]);
    __syncthreads();  // drains rbc_part atomics before counter bump
    if (tid == 0) lastflag = (atomicAdd(counter, 1) == 255);
    __syncthreads();
    if (!lastflag) return;
    const int node = tid & 31, sub = tid >> 5;
    float vv = 0.f;
#pragma unroll
    for (int g = 0; g < 8; g++)
        vv += atomicAdd(&rbc_part[(sub * 8 + g) * 32 + node], 0.f);  // coherent read
    red[sub][node] = vv;
    __syncthreads();
    if (tid < 32) {
        float acc = 0.f;
#pragma unroll
        for (int sb = 0; sb < 8; sb++) acc += red[sb][tid];
        float tot = acc;
#pragma unroll
        for (int mask = 1; mask < 32; mask <<= 1) tot += __shfl_xor(tot, mask, 32);
        out[tid] = acc / tot;
    }
}

extern "C" void kernel_launch(void* const* d_in, const int* in_sizes, int n_in,
                              void* d_out, int out_size, void* d_ws, size_t ws_size,
                              hipStream_t stream) {
    const float* emb = (const float*)d_in[0];
    const int* edges = (const int*)d_in[1];
    const float* w1 = (const float*)d_in[2];
    const float* b1 = (const float*)d_in[3];
    const float* w2 = (const float*)d_in[4];
    const float* b2 = (const float*)d_in[5];
    const float* w3 = (const float*)d_in[6];
    const float* b3 = (const float*)d_in[7];
    const float* fc1_w = (const float*)d_in[8];
    const float* fc1_b = (const float*)d_in[9];
    const float* fc2_w = (const float*)d_in[10];
    const float* fc2_b = (const float*)d_in[11];
    const float* fc3_w = (const float*)d_in[12];
    const float* fc3_b = (const float*)d_in[13];
    const float* fc4_w = (const float*)d_in[14];
    const float* fc4_b = (const float*)d_in[15];

    float* ws = (float*)d_ws;
    float* F = ws;
    float* preds = ws + PREDS_OFF;
    float* rbc_part = ws + RBCP_OFF;
    int* counter = (int*)(ws + CNT_OFF);
    unsigned short* W1p = (unsigned short*)(ws + W1P_OFF);
    unsigned short* W2p = (unsigned short*)(ws + W2P_OFF);
    unsigned short* W3p = (unsigned short*)(ws + W3P_OFF);
    float* out = (float*)d_out;

    prep_all<<<dim3(641), dim3(256), 0, stream>>>(emb, w1, fc1_w, fc2_w, fc3_w,
                                                  F, W1p, W2p, W3p, rbc_part);
    mlp_kernel<<<dim3(4096), dim3(256), 0, stream>>>(
        F, edges, b1, w2, b2, w3, b3, fc1_b, fc2_b, fc3_b,
        fc4_w, fc4_b, W1p, W2p, W3p, preds);
    prop_norm<<<dim3(256), dim3(256), 0, stream>>>(edges, preds, rbc_part, counter, out);
}

// Round 16
// 167.344 us; speedup vs baseline: 1.4048x; 1.1239x over previous
//
#include <hip/hip_runtime.h>

// ---- ws layout (float offsets) ----
constexpr int F_ELEMS = 4 * 32 * 4 * 48;            // padded-48 conv1 tables
constexpr int PREDS_OFF = F_ELEMS;                  // 24576
constexpr int RBCP_OFF = PREDS_OFF + 1024 * 256;    // rbc_part[64][32]
constexpr int CNT_OFF = RBCP_OFF + 2048;            // completion counter (+pad)
constexpr int W1P_OFF = CNT_OFF + 16;               // fc1 A-frags: 4096 shorts = 2048 f
constexpr int W2P_OFF = W1P_OFF + 2048;             // fc2 A-frags: 32768 shorts = 16384 f
constexpr int W3P_OFF = W2P_OFF + 16384;            // fc3 A-frags: 32768 shorts

typedef __attribute__((ext_vector_type(8))) short short8;
typedef __attribute__((ext_vector_type(4))) short short4v;
typedef __attribute__((ext_vector_type(4))) float f32x4;

__device__ __forceinline__ unsigned short f2bf(float x) {  // RNE bf16
    unsigned u = __float_as_uint(x);
    u += 0x7FFF + ((u >> 16) & 1);
    return (unsigned short)(u >> 16);
}

// ---------------- Kernel 0: all preprocessing (single-bf16 weights) ----------------
// b<96: F tables. b<112: W1p (4096). b<240: W2p (32768). b<368: W3p (32768). b==368: zero.
__global__ void prep_all(const float* __restrict__ emb, const float* __restrict__ w1,
                         const float* __restrict__ fc1_w, const float* __restrict__ fc2_w,
                         const float* __restrict__ fc3_w,
                         float* __restrict__ F, unsigned short* __restrict__ W1p,
                         unsigned short* __restrict__ W2p, unsigned short* __restrict__ W3p,
                         float* __restrict__ rbcp_zero) {
    int b = blockIdx.x;
    if (b < 96) {
        int idx = b * 256 + threadIdx.x;  // 24576
        int i = idx % 48;
        int o = (idx / 48) % 4;
        int node = (idx / 192) % 32;
        int c = idx / 6144;
        float acc = 0.f;
        if (i < 46) {
#pragma unroll
            for (int k = 0; k < 3; k++) acc += w1[(o * 4 + c) * 3 + k] * emb[node * 96 + 2 * i + k];
        }
        F[idx] = acc;
        return;
    }
    if (b < 112) {  // fc1 A-layout, K padded 16->32, single bf16
        int t = (b - 96) * 256 + threadIdx.x;  // 4096
        int j = t & 7, lane = (t >> 3) & 63, mt = t >> 9;
        int k = (lane >> 4) * 8 + j, n = mt * 16 + (lane & 15);
        float w = (k < 16) ? fc1_w[k * 128 + n] : 0.f;
        W1p[t] = f2bf(w);
        return;
    }
    if (b < 240) {  // fc2 A-layout [16mt][4ks], single bf16
        int t = (b - 112) * 256 + threadIdx.x;  // 32768
        int j = t & 7, lane = (t >> 3) & 63, ks = (t >> 9) & 3, mt = t >> 11;
        int k = ks * 32 + (lane >> 4) * 8 + j, n = mt * 16 + (lane & 15);
        W2p[t] = f2bf(fc2_w[k * 256 + n]);
        return;
    }
    if (b < 368) {  // fc3 A-layout [8mt][8ks], single bf16
        int t = (b - 240) * 256 + threadIdx.x;  // 32768
        int j = t & 7, lane = (t >> 3) & 63, ks = (t >> 9) & 7, mt = t >> 12;
        int k = ks * 32 + (lane >> 4) * 8 + j, n = mt * 16 + (lane & 15);
        W3p[t] = f2bf(fc3_w[k * 128 + n]);
        return;
    }
    for (int k = threadIdx.x; k < 2064; k += 256) rbcp_zero[k] = 0.f;  // rbc_part + counter
}

// ---------------- Kernel 1: r11 structure, single-bf16 weights (half the MFMAs).
// Established dead ends (do not retry): multi-chunk loop (r10: spills), min-waves=6
// (r12: VGPR clamp+spill), 64-wide quarters (r14: occupancy flat, +13us), fused prop
// (r8: +19us), one-block-per-pair (r10). ----------------
__global__ __launch_bounds__(256, 4)
void mlp_kernel(const float* __restrict__ F, const int* __restrict__ edges,
                const float* __restrict__ b1v,
                const float* __restrict__ w2, const float* __restrict__ b2,
                const float* __restrict__ w3, const float* __restrict__ b3,
                const float* __restrict__ fc1_b, const float* __restrict__ fc2_b,
                const float* __restrict__ fc3_b,
                const float* __restrict__ fc4_w, const float* __restrict__ fc4_b,
                const unsigned short* __restrict__ W1p, const unsigned short* __restrict__ W2p,
                const unsigned short* __restrict__ W3p,
                float* __restrict__ preds) {
    // LDS (floats): [0,4096) X3-half region, X1 aliases its head; [4096,8192) X2; [8192,8448) part
    __shared__ __align__(16) float smem[8448];
    unsigned short* X1 = (unsigned short*)smem;
    unsigned short* X3h = (unsigned short*)smem;
    unsigned short* X2 = (unsigned short*)(smem + 4096);
    float* part = smem + 8192;

    const int tid = threadIdx.x;
    const int p = blockIdx.x >> 2;
    const int e0 = (blockIdx.x & 3) * 64;
    const int s = p >> 5, t = p & 31;
    if (s == t) return;

    const int gsample = tid >> 2, o = tid & 3;  // conv roles
    float h1[23];
    // ---- conv1: table sum (float4 loads, padded-48 rows) + pool -> regs ----
    {
        const int e = e0 + gsample;
        const int u = edges[2 * e], v = edges[2 * e + 1];
        const f32x4* F0 = (const f32x4*)(F + ((0 * 32 + s) * 4 + o) * 48);
        const f32x4* F1 = (const f32x4*)(F + ((1 * 32 + t) * 4 + o) * 48);
        const f32x4* F2 = (const f32x4*)(F + ((2 * 32 + u) * 4 + o) * 48);
        const f32x4* F3 = (const f32x4*)(F + ((3 * 32 + v) * 4 + o) * 48);
        const float bb = b1v[o];
        float pre[46];
#pragma unroll
        for (int q = 0; q < 12; q++) {
            f32x4 x = F0[q] + F1[q] + F2[q] + F3[q];
#pragma unroll
            for (int z = 0; z < 4; z++) {
                int i = 4 * q + z;
                if (i < 46) pre[i] = fmaxf(x[z] + bb, 0.f);
            }
        }
#pragma unroll
        for (int j = 0; j < 23; j++) h1[j] = fmaxf(pre[2 * j], pre[2 * j + 1]);
    }
    float h2[10];
    // ---- conv2: cross-channel via shfl_xor (4-lane groups), sliding ring ----
    {
        float wm[4][3];  // wm[m][k] = w2[o][o^m][k]
#pragma unroll
        for (int m = 0; m < 4; m++)
#pragma unroll
            for (int k = 0; k < 3; k++) wm[m][k] = w2[o * 12 + (o ^ m) * 3 + k];
        const float bb = b2[o];
        float win[4][3];
#pragma unroll
        for (int j = 0; j < 2; j++) {
            float x = h1[j];
            win[0][j] = x;
            win[1][j] = __shfl_xor(x, 1, 64);
            win[2][j] = __shfl_xor(x, 2, 64);
            win[3][j] = __shfl_xor(x, 3, 64);
        }
        float pre[20];
#pragma unroll
        for (int i = 0; i < 20; i++) {
            float x = h1[i + 2];
            win[0][(i + 2) % 3] = x;
            win[1][(i + 2) % 3] = __shfl_xor(x, 1, 64);
            win[2][(i + 2) % 3] = __shfl_xor(x, 2, 64);
            win[3][(i + 2) % 3] = __shfl_xor(x, 3, 64);
            float acc = bb;
#pragma unroll
            for (int m = 0; m < 4; m++)
#pragma unroll
                for (int k = 0; k < 3; k++)
                    acc = fmaf(wm[m][k], win[m][(i + k) % 3], acc);
            pre[i] = fmaxf(acc, 0.f);
        }
#pragma unroll
        for (int j = 0; j < 10; j++) h2[j] = fmaxf(pre[2 * j], pre[2 * j + 1]);
    }
    // ---- conv3 + pool -> X1 (bf16 B-frag layout, K 16 padded to 32) ----
    {
        float wm[4][3];
#pragma unroll
        for (int m = 0; m < 4; m++)
#pragma unroll
            for (int k = 0; k < 3; k++) wm[m][k] = w3[o * 12 + (o ^ m) * 3 + k];
        const float bb = b3[o];
        float win[4][3];
#pragma unroll
        for (int j = 0; j < 2; j++) {
            float x = h2[j];
            win[0][j] = x;
            win[1][j] = __shfl_xor(x, 1, 64);
            win[2][j] = __shfl_xor(x, 2, 64);
            win[3][j] = __shfl_xor(x, 3, 64);
        }
        float pre[8];
#pragma unroll
        for (int i = 0; i < 8; i++) {
            float x = h2[i + 2];
            win[0][(i + 2) % 3] = x;
            win[1][(i + 2) % 3] = __shfl_xor(x, 1, 64);
            win[2][(i + 2) % 3] = __shfl_xor(x, 2, 64);
            win[3][(i + 2) % 3] = __shfl_xor(x, 3, 64);
            float acc = bb;
#pragma unroll
            for (int m = 0; m < 4; m++)
#pragma unroll
                for (int k = 0; k < 3; k++)
                    acc = fmaf(wm[m][k], win[m][(i + k) % 3], acc);
            pre[i] = fmaxf(acc, 0.f);
        }
        short4v pk;
#pragma unroll
        for (int l = 0; l < 4; l++)
            pk[l] = (short)f2bf(fmaxf(pre[2 * l], pre[2 * l + 1]));
        *(short4v*)(X1 + (((o >> 1) * 64 + gsample) * 8) + (o & 1) * 4) = pk;
        short4v z4 = (short4v){0, 0, 0, 0};  // k in [16,32) zeros
        *(short4v*)(X1 + ((((o >> 1) + 2) * 64 + gsample) * 8) + (o & 1) * 4) = z4;
    }
    __syncthreads();  // barrier 1: X1 visible to all waves
    const int lane = tid & 63, wave = tid >> 6;
    const int mrow = lane & 15, quad = lane >> 4;
    // ---- fc1 MFMA: A=W1p (8 mt, wave owns 2), B=X1 ----
    {
        const short8* W1v = (const short8*)W1p;
        short8 bnt[4];
#pragma unroll
        for (int nt = 0; nt < 4; nt++)
            bnt[nt] = *(const short8*)(X1 + (quad * 64 + nt * 16 + mrow) * 8);
        f32x4 acc1[2][4];
#pragma unroll
        for (int a = 0; a < 2; a++)
#pragma unroll
            for (int b = 0; b < 4; b++) acc1[a][b] = (f32x4){0.f, 0.f, 0.f, 0.f};
#pragma unroll
        for (int mtl = 0; mtl < 2; mtl++) {
            const int mt = wave * 2 + mtl;
            short8 ah = W1v[mt * 64 + lane];
#pragma unroll
            for (int nt = 0; nt < 4; nt++)
                acc1[mtl][nt] = __builtin_amdgcn_mfma_f32_16x16x32_bf16(ah, bnt[nt], acc1[mtl][nt], 0, 0, 0);
        }
        // epilogue straight to X2 (disjoint region; no barrier needed)
#pragma unroll
        for (int mtl = 0; mtl < 2; mtl++) {
            const int mt = wave * 2 + mtl;
            const int n0 = mt * 16 + quad * 4;
            f32x4 b4 = *(const f32x4*)(fc1_b + n0);
#pragma unroll
            for (int nt = 0; nt < 4; nt++) {
                short4v pk;
#pragma unroll
                for (int r = 0; r < 4; r++)
                    pk[r] = (short)f2bf(fmaxf(acc1[mtl][nt][r] + b4[r], 0.f));
                *(short4v*)(X2 + ((n0 >> 3) * 64 + nt * 16 + mrow) * 8 + (n0 & 7)) = pk;
            }
        }
    }
    __syncthreads();  // barrier 2: X2 visible; X1 reads done (X3h writes may follow)
    // ---- fc2 -> fc3 in two K=128 halves through X3h ----
    const short8* W2v = (const short8*)W2p;
    const short8* W3v = (const short8*)W3p;
    f32x4 acc3[2][4];
#pragma unroll
    for (int a = 0; a < 2; a++)
#pragma unroll
        for (int b = 0; b < 4; b++) acc3[a][b] = (f32x4){0.f, 0.f, 0.f, 0.f};
#pragma unroll
    for (int h = 0; h < 2; h++) {
        // fc2 half: wave owns 2 of 8 mt in this half (full K=128 from X2)
        f32x4 acc2[2][4];
#pragma unroll
        for (int a = 0; a < 2; a++)
#pragma unroll
            for (int b = 0; b < 4; b++) acc2[a][b] = (f32x4){0.f, 0.f, 0.f, 0.f};
#pragma unroll
        for (int ks = 0; ks < 4; ks++) {
            short8 bfr[4];
#pragma unroll
            for (int nt = 0; nt < 4; nt++)
                bfr[nt] = *(const short8*)(X2 + ((ks * 4 + quad) * 64 + nt * 16 + mrow) * 8);
#pragma unroll
            for (int mtl = 0; mtl < 2; mtl++) {
                const int mt = h * 8 + wave * 2 + mtl;
                short8 ah = W2v[(mt * 4 + ks) * 64 + lane];
#pragma unroll
                for (int nt = 0; nt < 4; nt++)
                    acc2[mtl][nt] = __builtin_amdgcn_mfma_f32_16x16x32_bf16(ah, bfr[nt], acc2[mtl][nt], 0, 0, 0);
            }
        }
        // epilogue -> X3h (k-local = n - h*128)
#pragma unroll
        for (int mtl = 0; mtl < 2; mtl++) {
            const int mt = h * 8 + wave * 2 + mtl;
            const int n0 = mt * 16 + quad * 4;
            const int kl = n0 - h * 128;
            f32x4 b4 = *(const f32x4*)(fc2_b + n0);
#pragma unroll
            for (int nt = 0; nt < 4; nt++) {
                short4v pk;
#pragma unroll
                for (int r = 0; r < 4; r++)
                    pk[r] = (short)f2bf(fmaxf(acc2[mtl][nt][r] + b4[r], 0.f));
                *(short4v*)(X3h + ((kl >> 3) * 64 + nt * 16 + mrow) * 8 + (kl & 7)) = pk;
            }
        }
        __syncthreads();  // barrier 3/5: X3h half ready
        // fc3 accumulate this half's 4 ks
#pragma unroll
        for (int ksl = 0; ksl < 4; ksl++) {
            const int ks = h * 4 + ksl;
            short8 bfr[4];
#pragma unroll
            for (int nt = 0; nt < 4; nt++)
                bfr[nt] = *(const short8*)(X3h + ((ksl * 4 + quad) * 64 + nt * 16 + mrow) * 8);
#pragma unroll
            for (int mtl = 0; mtl < 2; mtl++) {
                const int mt = wave * 2 + mtl;
                short8 ah = W3v[(mt * 8 + ks) * 64 + lane];
#pragma unroll
                for (int nt = 0; nt < 4; nt++)
                    acc3[mtl][nt] = __builtin_amdgcn_mfma_f32_16x16x32_bf16(ah, bfr[nt], acc3[mtl][nt], 0, 0, 0);
            }
        }
        __syncthreads();  // barrier 4/6: X3h reads done before reuse / part writes
    }
    // ---- fused fc4 ----
    {
        float p4[4] = {0.f, 0.f, 0.f, 0.f};
#pragma unroll
        for (int mtl = 0; mtl < 2; mtl++) {
            const int mt = wave * 2 + mtl;
            const int n0 = mt * 16 + quad * 4;
            f32x4 b4 = *(const f32x4*)(fc3_b + n0);
            f32x4 w44 = *(const f32x4*)(fc4_w + n0);
#pragma unroll
            for (int nt = 0; nt < 4; nt++)
#pragma unroll
                for (int r = 0; r < 4; r++)
                    p4[nt] = fmaf(fmaxf(acc3[mtl][nt][r] + b4[r], 0.f), w44[r], p4[nt]);
        }
#pragma unroll
        for (int nt = 0; nt < 4; nt++) {
            p4[nt] += __shfl_xor(p4[nt], 16, 64);
            p4[nt] += __shfl_xor(p4[nt], 32, 64);
        }
        if (quad == 0) {
#pragma unroll
            for (int nt = 0; nt < 4; nt++)
                part[wave * 64 + nt * 16 + mrow] = p4[nt];
        }
    }
    __syncthreads();
    if (tid < 64) {
        float pred = part[tid] + part[64 + tid] + part[128 + tid] + part[192 + tid] + fc4_b[0];
        preds[p * 256 + e0 + tid] = pred;
    }
}

// ---------------- Kernel 2: propagation, one WAVE per pair (256 blocks) + fused normalize ----------------
__global__ __launch_bounds__(256)
void prop_norm(const int* __restrict__ edges, const float* __restrict__ preds,
               float* __restrict__ rbc_part, int* __restrict__ counter,
               float* __restrict__ out) {
    const int tid = threadIdx.x;
    const int wave = tid >> 6, lane = tid & 63;
    const int p = blockIdx.x * 4 + wave;
    const int s = p >> 5, t = p & 31;
    __shared__ float xw[4][32], xnw[4][32], raccw[4][32];
    __shared__ float red[8][32];
    __shared__ int lastflag;
    int u[4], v[4];
    float pr[4];
#pragma unroll
    for (int j = 0; j < 4; j++) {
        int e = lane + 64 * j;
        u[j] = edges[2 * e];
        v[j] = edges[2 * e + 1];
        pr[j] = preds[p * 256 + e];
    }
    if (lane < 32) { xw[wave][lane] = (lane == s) ? 1.f : 0.f; raccw[wave][lane] = 0.f; }
    const bool active = (s != t);
    for (int step = 0; step < 3; step++) {
        if (lane < 32) xnw[wave][lane] = 0.f;
        __syncthreads();
        if (active) {
#pragma unroll
            for (int j = 0; j < 4; j++)
                atomicAdd(&xnw[wave][v[j]], xw[wave][u[j]] * pr[j]);
        }
        __syncthreads();
        if (lane < 32) { raccw[wave][lane] += xnw[wave][lane]; xw[wave][lane] = xnw[wave][lane]; }
        __syncthreads();
    }
    if (active && lane < 32) atomicAdd(&rbc_part[(p & 63) * 32 + lane], raccw[wave][lane]);
    __syncthreads();  // drains rbc_part atomics before counter bump
    if (tid == 0) lastflag = (atomicAdd(counter, 1) == 255);
    __syncthreads();
    if (!lastflag) return;
    const int node = tid & 31, sub = tid >> 5;
    float vv = 0.f;
#pragma unroll
    for (int g = 0; g < 8; g++)
        vv += atomicAdd(&rbc_part[(sub * 8 + g) * 32 + node], 0.f);  // coherent read
    red[sub][node] = vv;
    __syncthreads();
    if (tid < 32) {
        float acc = 0.f;
#pragma unroll
        for (int sb = 0; sb < 8; sb++) acc += red[sb][tid];
        float tot = acc;
#pragma unroll
        for (int mask = 1; mask < 32; mask <<= 1) tot += __shfl_xor(tot, mask, 32);
        out[tid] = acc / tot;
    }
}

extern "C" void kernel_launch(void* const* d_in, const int* in_sizes, int n_in,
                              void* d_out, int out_size, void* d_ws, size_t ws_size,
                              hipStream_t stream) {
    const float* emb = (const float*)d_in[0];
    const int* edges = (const int*)d_in[1];
    const float* w1 = (const float*)d_in[2];
    const float* b1 = (const float*)d_in[3];
    const float* w2 = (const float*)d_in[4];
    const float* b2 = (const float*)d_in[5];
    const float* w3 = (const float*)d_in[6];
    const float* b3 = (const float*)d_in[7];
    const float* fc1_w = (const float*)d_in[8];
    const float* fc1_b = (const float*)d_in[9];
    const float* fc2_w = (const float*)d_in[10];
    const float* fc2_b = (const float*)d_in[11];
    const float* fc3_w = (const float*)d_in[12];
    const float* fc3_b = (const float*)d_in[13];
    const float* fc4_w = (const float*)d_in[14];
    const float* fc4_b = (const float*)d_in[15];

    float* ws = (float*)d_ws;
    float* F = ws;
    float* preds = ws + PREDS_OFF;
    float* rbc_part = ws + RBCP_OFF;
    int* counter = (int*)(ws + CNT_OFF);
    unsigned short* W1p = (unsigned short*)(ws + W1P_OFF);
    unsigned short* W2p = (unsigned short*)(ws + W2P_OFF);
    unsigned short* W3p = (unsigned short*)(ws + W3P_OFF);
    float* out = (float*)d_out;

    prep_all<<<dim3(369), dim3(256), 0, stream>>>(emb, w1, fc1_w, fc2_w, fc3_w,
                                                  F, W1p, W2p, W3p, rbc_part);
    mlp_kernel<<<dim3(4096), dim3(256), 0, stream>>>(
        F, edges, b1, w2, b2, w3, b3, fc1_b, fc2_b, fc3_b,
        fc4_w, fc4_b, W1p, W2p, W3p, preds);
    prop_norm<<<dim3(256), dim3(256), 0, stream>>>(edges, preds, rbc_part, counter, out);
}